// Round 11
// baseline (465.144 us; speedup 1.0000x reference)
//
#include <hip/hip_runtime.h>
#include <stdint.h>

#define DEV_INLINE __device__ __forceinline__

constexpr int cS0 = 200000, cD0 = 40000, cD1 = 8192;
constexpr int cE0 = 640000, cE1 = 131072;
constexpr int cDIN = 256, cDH = 512, cDOUT = 256;

// padded per-relation node-region sizes
constexpr int P0 = 40960, P1 = 9216;
constexpr int NTOT = 2 * P0 + 2 * P1;   // 100352
constexpr int NBLK = NTOT / 1024;       // 98
constexpr int ETOT = 2 * cE0 + 2 * cE1; // 1542144
constexpr int MPADI = 40064;            // cD0 padded for BM=128 tiles

// front kernel partition
constexpr long N8   = (long)cS0 * cDIN / 8;      // 8-float units per table (6.4M)
constexpr long NQB  = (long)MPADI * cDIN / 8;    // units needing bf16 mini copy
constexpr int NCVT_BLK = 4096;                   // grid-stride resident blocks
constexpr int NWT_BLK  = 1024;                   // 32x32 transpose tiles (128/slot * 8)
constexpr int NDEG_BLK = (ETOT + 255) / 256;     // 6024
constexpr long CSTR = (long)NCVT_BLK * 256;      // cvt grid stride

typedef __attribute__((ext_vector_type(8))) short bf16x8_t;
typedef __attribute__((ext_vector_type(4))) float f32x4_t;
typedef __attribute__((ext_vector_type(2))) float fp32x2_t;

#if __has_builtin(__builtin_amdgcn_cvt_pk_f32_fp8) && __has_builtin(__builtin_amdgcn_cvt_pk_fp8_f32)
#define HWFP8 1
#else
#define HWFP8 0
#endif

DEV_INLINE float bf2f(unsigned short u) {
    union { unsigned int i; float f; } x; x.i = ((unsigned int)u) << 16; return x.f;
}
DEV_INLINE unsigned short f2bf(float f) {
    union { float f; unsigned int i; } x; x.f = f;
    unsigned int r = x.i + 0x7FFF + ((x.i >> 16) & 1);
    return (unsigned short)(r >> 16);
}

#if !HWFP8
DEV_INLINE unsigned char f2fp8s(float f) {
    union { float f; unsigned int u; } x; x.f = f;
    unsigned int s = (x.u >> 24) & 0x80;
    x.u &= 0x7FFFFFFF;
    if (x.f >= 448.f) return (unsigned char)(s | 0x7E);
    int e = (int)(x.u >> 23) - 127;
    if (e < -6) {
        int m = (int)(x.f * 512.0f + 0.5f);
        return (unsigned char)(m >= 8 ? (s | 0x08) : (s | m));
    }
    unsigned int r = x.u + 0x7FFFF + ((x.u >> 20) & 1);
    e = (int)(r >> 23) - 127;
    if (e > 8) return (unsigned char)(s | 0x7E);
    return (unsigned char)(s | ((unsigned)(e + 7) << 3) | ((r >> 20) & 7));
}
DEV_INLINE float fp82f(unsigned char b) {
    int e = (b >> 3) & 15, m = b & 7;
    float f;
    if (e == 0) f = (float)m * 0x1p-9f;
    else { union { unsigned int u; float f; } x; x.u = ((unsigned int)(e + 120) << 23) | ((unsigned int)m << 20); f = x.f; }
    return (b & 0x80) ? -f : f;
}
#endif

DEV_INLINE uint2 pack8_fp8(float4 u, float4 v) {
    uint2 q;
#if HWFP8
    int w0 = __builtin_amdgcn_cvt_pk_fp8_f32(u.x, u.y, 0, false);
    w0 = __builtin_amdgcn_cvt_pk_fp8_f32(u.z, u.w, w0, true);
    int w1 = __builtin_amdgcn_cvt_pk_fp8_f32(v.x, v.y, 0, false);
    w1 = __builtin_amdgcn_cvt_pk_fp8_f32(v.z, v.w, w1, true);
    q.x = (unsigned)w0; q.y = (unsigned)w1;
#else
    unsigned char b[8] = { f2fp8s(u.x), f2fp8s(u.y), f2fp8s(u.z), f2fp8s(u.w),
                           f2fp8s(v.x), f2fp8s(v.y), f2fp8s(v.z), f2fp8s(v.w) };
    q.x = b[0] | (b[1] << 8) | (b[2] << 16) | ((unsigned)b[3] << 24);
    q.y = b[4] | (b[5] << 8) | (b[6] << 16) | ((unsigned)b[7] << 24);
#endif
    return q;
}

DEV_INLINE void gload_lds16(const void* g, void* l) {
    __builtin_amdgcn_global_load_lds(
        (__attribute__((address_space(1))) void*)(uintptr_t)g,
        (__attribute__((address_space(3))) void*)(uintptr_t)l,
        16, 0, 0);
}

struct WPtrs { const float* w[8]; };

// ---------------- fused front ----------------
// cvt: grid-stride resident loop, 4 independent 16B loads/iter (both tables).
// wt:  LDS 32x33 tile transpose, coalesced read AND write.
// deg: edge-dst histogram.

__global__ __launch_bounds__(256) void k_front(
    const float* __restrict__ xu, const float* __restrict__ xm,
    unsigned char* __restrict__ qu, unsigned char* __restrict__ qm,
    unsigned short* __restrict__ mu, unsigned short* __restrict__ mm,
    WPtrs W, unsigned short* __restrict__ wt,
    const int* __restrict__ d0, const int* __restrict__ d1,
    const int* __restrict__ d2, const int* __restrict__ d3,
    int* __restrict__ deg) {
    __shared__ float tile[32][33];
    int b = blockIdx.x;
    if (b < NCVT_BLK) {
        long tid0 = (long)b * 256 + threadIdx.x;
        for (long i = tid0; i < N8; i += CSTR) {
            const float4* pu = (const float4*)(xu + i * 8);
            const float4* pm = (const float4*)(xm + i * 8);
            float4 u0 = pu[0], u1 = pu[1];      // 4 independent loads in flight
            float4 v0 = pm[0], v1 = pm[1];
            *(uint2*)(qu + i * 8) = pack8_fp8(u0, u1);
            *(uint2*)(qm + i * 8) = pack8_fp8(v0, v1);
            if (i < NQB) {
                union { unsigned short us[8]; uint4 q; } pk;
                pk.us[0] = f2bf(u0.x); pk.us[1] = f2bf(u0.y); pk.us[2] = f2bf(u0.z); pk.us[3] = f2bf(u0.w);
                pk.us[4] = f2bf(u1.x); pk.us[5] = f2bf(u1.y); pk.us[6] = f2bf(u1.z); pk.us[7] = f2bf(u1.w);
                *(uint4*)(mu + i * 8) = pk.q;
                pk.us[0] = f2bf(v0.x); pk.us[1] = f2bf(v0.y); pk.us[2] = f2bf(v0.z); pk.us[3] = f2bf(v0.w);
                pk.us[4] = f2bf(v1.x); pk.us[5] = f2bf(v1.y); pk.us[6] = f2bf(v1.z); pk.us[7] = f2bf(v1.w);
                *(uint4*)(mm + i * 8) = pk.q;
            }
        }
        return;
    }
    b -= NCVT_BLK;
    if (b < NWT_BLK) {                            // W [K][N] fp32 -> Wt [N][K] bf16, LDS transpose
        int slot = b >> 7, t2 = b & 127;
        int K, N, k0, n0;
        if (slot < 4) { K = cDIN; N = cDH;  k0 = (t2 & 7) * 32;  n0 = (t2 >> 3) * 32; }
        else          { K = cDH;  N = cDOUT; k0 = (t2 & 15) * 32; n0 = (t2 >> 4) * 32; }
        const float* Wp = W.w[slot];
        int c = threadIdx.x & 31, ty = threadIdx.x >> 5;
#pragma unroll
        for (int it = 0; it < 4; ++it) {
            int r = it * 8 + ty;
            tile[r][c] = Wp[(size_t)(k0 + r) * N + n0 + c];   // coalesced in c
        }
        __syncthreads();
        unsigned short* wo = wt + (size_t)slot * 131072;
#pragma unroll
        for (int it = 0; it < 4; ++it) {
            int r = it * 8 + ty;
            wo[(size_t)(n0 + r) * K + k0 + c] = f2bf(tile[c][r]);  // coalesced in c
        }
        return;
    }
    b -= NWT_BLK;
    int i = b * 256 + threadIdx.x;
    if (i >= ETOT) return;
    const int* dp; int base, noff;
    if (i < cE0)                { dp = d0; base = 0;             noff = 0; }
    else if (i < 2 * cE0)       { dp = d1; base = cE0;           noff = P0; }
    else if (i < 2 * cE0 + cE1) { dp = d2; base = 2 * cE0;       noff = 2 * P0; }
    else                        { dp = d3; base = 2 * cE0 + cE1; noff = 2 * P0 + P1; }
    atomicAdd(&deg[noff + dp[i - base]], 1);
}

// ---------------- CSR scan + fill ----------------

__global__ __launch_bounds__(256) void k_scanA(const int* __restrict__ deg, int* __restrict__ off,
                                               int* __restrict__ btot) {
    __shared__ int buf[256];
    int t = threadIdx.x;
    long base = (long)blockIdx.x * 1024;
    int4 v = *(const int4*)(deg + base + t * 4);
    int s1 = v.x + v.y, s2 = s1 + v.z, ts = s2 + v.w;
    buf[t] = ts; __syncthreads();
    for (int o = 1; o < 256; o <<= 1) {
        int u = (t >= o) ? buf[t - o] : 0;
        __syncthreads(); buf[t] += u; __syncthreads();
    }
    int ex = buf[t] - ts;
    int4 w; w.x = ex; w.y = ex + v.x; w.z = ex + s1; w.w = ex + s2;
    *(int4*)(off + base + t * 4) = w;
    if (t == 255) btot[blockIdx.x] = buf[255];
}

__global__ void k_scanB(int* __restrict__ bt) {
    __shared__ int buf[128];
    __shared__ int seg[128];
    int t = threadIdx.x;
    int s = (t >= 89) ? 3 : (t >= 80) ? 2 : (t >= 40) ? 1 : 0;
    int v = (t < NBLK) ? bt[t] : 0;
    buf[t] = v; seg[t] = s; __syncthreads();
    for (int o = 1; o < 128; o <<= 1) {
        int u = 0;
        if (t >= o && seg[t - o] == s) u = buf[t - o];
        __syncthreads(); buf[t] += u; __syncthreads();
    }
    if (t < NBLK) bt[t] = buf[t] - v;   // exclusive within segment
}

__global__ __launch_bounds__(256) void k_scanC(int* __restrict__ off, const int* __restrict__ bt) {
    int t = threadIdx.x;
    long base = (long)blockIdx.x * 1024;
    int bo = bt[blockIdx.x];
    int4 v = *(int4*)(off + base + t * 4);
    v.x += bo; v.y += bo; v.z += bo; v.w += bo;
    *(int4*)(off + base + t * 4) = v;
}

__global__ __launch_bounds__(256) void k_fill_all(
    const int* __restrict__ s0, const int* __restrict__ d0, const int* __restrict__ s1, const int* __restrict__ d1,
    const int* __restrict__ s2, const int* __restrict__ d2, const int* __restrict__ s3, const int* __restrict__ d3,
    const int* __restrict__ off, int* __restrict__ cur, int* __restrict__ csr) {
    int i = blockIdx.x * 256 + threadIdx.x;
    if (i >= ETOT) return;
    const int* sp; const int* dp; int base, noff, cbase;
    if (i < cE0)                { sp = s0; dp = d0; base = 0;             noff = 0;           cbase = 0; }
    else if (i < 2 * cE0)       { sp = s1; dp = d1; base = cE0;           noff = P0;          cbase = cE0; }
    else if (i < 2 * cE0 + cE1) { sp = s2; dp = d2; base = 2 * cE0;       noff = 2 * P0;      cbase = 2 * cE0; }
    else                        { sp = s3; dp = d3; base = 2 * cE0 + cE1; noff = 2 * P0 + P1; cbase = 2 * cE0 + cE1; }
    int li = i - base;
    int d = dp[li];
    int p = atomicAdd(&cur[noff + d], 1);
    csr[cbase + off[noff + d] + p] = sp[li];
}

// ---------------- layer-1 mean aggregation: fp8 gather (L3-resident tables), bf16 out ----------------

__global__ __launch_bounds__(256) void k_agg1(
    const unsigned char* __restrict__ q0, const int* __restrict__ off0, const int* __restrict__ csr0,
    unsigned short* __restrict__ o0,
    const unsigned char* __restrict__ q1, const int* __restrict__ off1, const int* __restrict__ csr1,
    unsigned short* __restrict__ o1) {
    constexpr int U = 16;
    int nb = cD0 / 4;
    int b = blockIdx.x;
    const unsigned char* xq; const int* off; const int* csr; unsigned short* out;
    if (b >= nb) { xq = q1; off = off1; csr = csr1; out = o1; b -= nb; }
    else         { xq = q0; off = off0; csr = csr0; out = o0; }
    int lane = threadIdx.x & 63;
    int d = b * 4 + (threadIdx.x >> 6);

    float a0 = 0.f, a1 = 0.f, a2 = 0.f, a3 = 0.f;
    int p0 = off[d], p1 = off[d + 1];

    for (int p = p0; p < p1; p += U) {
        int idx[U];
#pragma unroll
        for (int u = 0; u < U; ++u) {
            int q = p + u;
            idx[u] = (q < p1) ? csr[q] : -1;
        }
#pragma unroll
        for (int u = 0; u < U; ++u) {
            if (idx[u] >= 0) {
                unsigned int w = *(const unsigned int*)(xq + (size_t)idx[u] * cDIN + lane * 4);
#if HWFP8
                fp32x2_t lo = __builtin_amdgcn_cvt_pk_f32_fp8((int)w, false);
                fp32x2_t hi = __builtin_amdgcn_cvt_pk_f32_fp8((int)w, true);
                a0 += lo[0]; a1 += lo[1]; a2 += hi[0]; a3 += hi[1];
#else
                a0 += fp82f(w & 0xFF); a1 += fp82f((w >> 8) & 0xFF);
                a2 += fp82f((w >> 16) & 0xFF); a3 += fp82f(w >> 24);
#endif
            }
        }
    }
    int dg = p1 - p0;
    float sc = 1.0f / (float)(dg > 1 ? dg : 1);
    union { unsigned short us[4]; uint2 v2; } pk;
    pk.us[0] = f2bf(a0 * sc); pk.us[1] = f2bf(a1 * sc);
    pk.us[2] = f2bf(a2 * sc); pk.us[3] = f2bf(a3 * sc);
    *(uint2*)(out + (size_t)d * cDIN + (size_t)lane * 4) = pk.v2;
}

// ---------------- layer-2 mean aggregation (bf16, K=512) ----------------

__global__ __launch_bounds__(256) void k_agg2(
    const unsigned short* __restrict__ x0, const int* __restrict__ off0, const int* __restrict__ csr0,
    unsigned short* __restrict__ o0,
    const unsigned short* __restrict__ x1, const int* __restrict__ off1, const int* __restrict__ csr1,
    unsigned short* __restrict__ o1) {
    constexpr int K = cDH, U = 8;
    int nb = cD1 / 4;
    int b = blockIdx.x;
    const unsigned short* xs; const int* off; const int* csr; unsigned short* out;
    if (b >= nb) { xs = x1; off = off1; csr = csr1; out = o1; b -= nb; }
    else         { xs = x0; off = off0; csr = csr0; out = o0; }
    int lane = threadIdx.x & 63;
    int d = b * 4 + (threadIdx.x >> 6);

    float acc[8];
#pragma unroll
    for (int i = 0; i < 8; i++) acc[i] = 0.f;
    int p0 = off[d], p1 = off[d + 1];

    for (int p = p0; p < p1; p += U) {
        int idx[U];
#pragma unroll
        for (int u = 0; u < U; ++u) {
            int q = p + u;
            idx[u] = (q < p1) ? csr[q] : -1;
        }
#pragma unroll
        for (int u = 0; u < U; ++u) {
            if (idx[u] >= 0) {
                uint4 v = *(const uint4*)(xs + (size_t)idx[u] * K + lane * 8);
                const unsigned short* us = (const unsigned short*)&v;
#pragma unroll
                for (int i = 0; i < 8; ++i) acc[i] += bf2f(us[i]);
            }
        }
    }
    int dg = p1 - p0;
    float sc = 1.0f / (float)(dg > 1 ? dg : 1);
    union { unsigned short us[8]; uint4 v4; } pk;
#pragma unroll
    for (int i = 0; i < 8; i++) pk.us[i] = f2bf(acc[i] * sc);
    *(uint4*)(out + (size_t)d * K + (size_t)lane * 8) = pk.v4;
}

// ---------------- fused SAGE GEMM (MFMA bf16), 2 relations per launch ----------------

template <int BM, int KSEG, int N, bool OUT_BF16, bool RELU>
__global__ __launch_bounds__(256) void k_gemm2(
    const unsigned short* __restrict__ aself0, const unsigned short* __restrict__ aagg0,
    const unsigned short* __restrict__ bts0, const unsigned short* __restrict__ btn0,
    const float* __restrict__ bias0, void* __restrict__ out0,
    const unsigned short* __restrict__ aself1, const unsigned short* __restrict__ aagg1,
    const unsigned short* __restrict__ bts1, const unsigned short* __restrict__ btn1,
    const float* __restrict__ bias1, void* __restrict__ out1,
    int mtiles) {
    constexpr int BN = 128, BK = 64;
    constexpr int H = KSEG / BK, NSTEP = 2 * H;
    constexpr int WROWS = BM / 2, FM = WROWS / 16;
    constexpr int AIT = BM / 32;
    __shared__ __align__(16) unsigned short As[2][BM * BK];
    __shared__ __align__(16) unsigned short Bs[2][BN * BK];

    const int tiles_n = N / BN;
    const int gpr = mtiles * tiles_n;
    int b = blockIdx.x;
    {
        int cpx = gridDim.x >> 3;
        b = (b & 7) * cpx + (b >> 3);
    }
    const unsigned short *aself, *aagg, *bts, *btn; const float* bias; void* out;
    if (b >= gpr) { b -= gpr; aself = aself1; aagg = aagg1; bts = bts1; btn = btn1; bias = bias1; out = out1; }
    else          {           aself = aself0; aagg = aagg0; bts = bts0; btn = btn0; bias = bias0; out = out0; }
    const int m0 = (b / tiles_n) * BM;
    const int n0 = (b % tiles_n) * BN;
    const int t = threadIdx.x, lane = t & 63, wave = t >> 6;
    const int wr = wave >> 1, wc = wave & 1;
    const int l15 = lane & 15, l4 = lane >> 4;

    f32x4_t acc[FM][4];
    const f32x4_t zero = {0.f, 0.f, 0.f, 0.f};
#pragma unroll
    for (int i = 0; i < FM; i++)
#pragma unroll
        for (int j = 0; j < 4; j++) acc[i][j] = zero;

    auto stage = [&](int buf, int s) {
        const int seg = (s >= H) ? 1 : 0;
        const int k0 = (s - seg * H) * BK;
        const unsigned short* A = seg ? aagg : aself;
        const unsigned short* B = seg ? btn : bts;
#pragma unroll
        for (int it = 0; it < AIT; ++it) {
            int c = it * 256 + t;
            int row = c >> 3;
            int lch = (c & 7) ^ (row & 7);
            gload_lds16(A + (size_t)(m0 + row) * KSEG + k0 + lch * 8,
                        (char*)&As[buf][0] + (it * 256 + wave * 64) * 16);
        }
#pragma unroll
        for (int it = 0; it < 4; ++it) {
            int c = it * 256 + t;
            int row = c >> 3;
            int lch = (c & 7) ^ (row & 7);
            gload_lds16(B + (size_t)(n0 + row) * KSEG + k0 + lch * 8,
                        (char*)&Bs[buf][0] + (it * 256 + wave * 64) * 16);
        }
    };

    int cur = 0;
    stage(0, 0);
    for (int s = 0; s < NSTEP; ++s) {
        __syncthreads();
        if (s + 1 < NSTEP) stage(cur ^ 1, s + 1);
        const char* Ab = (const char*)&As[cur][0];
        const char* Bb = (const char*)&Bs[cur][0];
        bf16x8_t a[FM][2], bb[4][2];
#pragma unroll
        for (int fm = 0; fm < FM; ++fm) {
            int row = wr * WROWS + fm * 16 + l15;
#pragma unroll
            for (int ks = 0; ks < 2; ++ks) {
                int pc = (ks * 4 + l4) ^ (row & 7);
                a[fm][ks] = *(const bf16x8_t*)(Ab + row * 128 + pc * 16);
            }
        }
#pragma unroll
        for (int fn = 0; fn < 4; ++fn) {
            int row = wc * 64 + fn * 16 + l15;
#pragma unroll
            for (int ks = 0; ks < 2; ++ks) {
                int pc = (ks * 4 + l4) ^ (row & 7);
                bb[fn][ks] = *(const bf16x8_t*)(Bb + row * 128 + pc * 16);
            }
        }
#pragma unroll
        for (int ks = 0; ks < 2; ++ks)
#pragma unroll
            for (int fm = 0; fm < FM; ++fm)
#pragma unroll
                for (int fn = 0; fn < 4; ++fn)
                    acc[fm][fn] = __builtin_amdgcn_mfma_f32_16x16x32_bf16(
                        a[fm][ks], bb[fn][ks], acc[fm][fn], 0, 0, 0);
        cur ^= 1;
    }

#pragma unroll
    for (int fm = 0; fm < FM; ++fm) {
#pragma unroll
        for (int fn = 0; fn < 4; ++fn) {
            int col = n0 + wc * 64 + fn * 16 + l15;
            float bv = bias[col];
            f32x4_t v = acc[fm][fn];
#pragma unroll
            for (int r = 0; r < 4; ++r) {
                int rowg = m0 + wr * WROWS + fm * 16 + l4 * 4 + r;
                float o = v[r] + bv;
                if (RELU) o = fmaxf(o, 0.f);
                if constexpr (OUT_BF16)
                    ((unsigned short*)out)[(size_t)rowg * N + col] = f2bf(o);
                else
                    ((float*)out)[(size_t)rowg * N + col] = o;
            }
        }
    }
}

// ---------------- launch ----------------

extern "C" void kernel_launch(void* const* d_in, const int* in_sizes, int n_in,
                              void* d_out, int out_size, void* d_ws, size_t ws_size,
                              hipStream_t stream) {
    const float* x_user  = (const float*)d_in[0];
    const float* x_movie = (const float*)d_in[1];
    const float* W1r_n = (const float*)d_in[2];
    const float* W1r_s = (const float*)d_in[3];
    const float* b1r   = (const float*)d_in[4];
    const float* W1b_n = (const float*)d_in[5];
    const float* W1b_s = (const float*)d_in[6];
    const float* b1b   = (const float*)d_in[7];
    const float* W2r_n = (const float*)d_in[8];
    const float* W2r_s = (const float*)d_in[9];
    const float* b2r   = (const float*)d_in[10];
    const float* W2b_n = (const float*)d_in[11];
    const float* W2b_s = (const float*)d_in[12];
    const float* b2b   = (const float*)d_in[13];
    const int* e0r_src = (const int*)d_in[14];
    const int* e0r_dst = (const int*)d_in[15];
    const int* e0b_src = (const int*)d_in[16];
    const int* e0b_dst = (const int*)d_in[17];
    const int* e1r_src = (const int*)d_in[18];
    const int* e1r_dst = (const int*)d_in[19];
    const int* e1b_src = (const int*)d_in[20];
    const int* e1b_dst = (const int*)d_in[21];

    // ---- workspace layout ----
    constexpr size_t MPAD = MPADI;
    char* w = (char*)d_ws;
    size_t o = 0;
    auto take = [&](size_t bytes) -> void* {
        void* p = w + o; o += (bytes + 255) & ~(size_t)255; return p;
    };
    unsigned short* h1m   = (unsigned short*)take(MPAD * cDH * 2);
    unsigned short* h1u   = (unsigned short*)take(MPAD * cDH * 2);
    unsigned short* aggR  = (unsigned short*)take(MPAD * cDIN * 2);
    unsigned short* aggB  = (unsigned short*)take(MPAD * cDIN * 2);
    unsigned short* agg2R = (unsigned short*)take((size_t)cD1 * cDH * 2);
    unsigned short* agg2B = (unsigned short*)take((size_t)cD1 * cDH * 2);
    unsigned short* wt    = (unsigned short*)take((size_t)8 * 131072 * 2);
    unsigned char*  qu    = (unsigned char*)take((size_t)cS0 * cDIN);      // fp8 tables
    unsigned char*  qm    = (unsigned char*)take((size_t)cS0 * cDIN);
    unsigned short* xub   = (unsigned short*)take(MPAD * cDIN * 2);        // bf16 minis
    unsigned short* xmb   = (unsigned short*)take(MPAD * cDIN * 2);
    int* deg_all = (int*)take((size_t)2 * NTOT * 4);   // deg + cur contiguous
    int* cur_all = deg_all + NTOT;
    int* off_all = (int*)take((size_t)NTOT * 4);
    int* btot    = (int*)take(512);
    int* csr_all = (int*)take((size_t)ETOT * 4);
    if (ws_size < o) return;  // insufficient workspace: fail visibly

    const int* off0 = off_all;
    const int* off1 = off_all + P0;
    const int* off2 = off_all + 2 * P0;
    const int* off3 = off_all + 2 * P0 + P1;
    const int* csr0 = csr_all;
    const int* csr1 = csr_all + cE0;
    const int* csr2 = csr_all + 2 * cE0;
    const int* csr3 = csr_all + 2 * cE0 + cE1;

    float* out_u2 = (float*)d_out;
    float* out_m2 = (float*)d_out + (size_t)cD1 * cDOUT;

    // 1) zero deg+cur
    hipMemsetAsync(deg_all, 0, (size_t)2 * NTOT * 4, stream);
    // 2) fused front: fp8+mini cvt (grid-stride) | wt LDS transpose | degree count
    WPtrs WP;
    WP.w[0] = W1r_s; WP.w[1] = W1r_n; WP.w[2] = W1b_s; WP.w[3] = W1b_n;
    WP.w[4] = W2r_s; WP.w[5] = W2r_n; WP.w[6] = W2b_s; WP.w[7] = W2b_n;
    k_front<<<NCVT_BLK + NWT_BLK + NDEG_BLK, 256, 0, stream>>>(
        x_user, x_movie, qu, qm, xub, xmb, WP, wt,
        e0r_dst, e0b_dst, e1r_dst, e1b_dst, deg_all);
    // 3-5) scans
    k_scanA<<<NBLK, 256, 0, stream>>>(deg_all, off_all, btot);
    k_scanB<<<1, 128, 0, stream>>>(btot);
    k_scanC<<<NBLK, 256, 0, stream>>>(off_all, btot);
    // 6) CSR fill
    k_fill_all<<<(ETOT + 255) / 256, 256, 0, stream>>>(
        e0r_src, e0r_dst, e0b_src, e0b_dst, e1r_src, e1r_dst, e1b_src, e1b_dst,
        off_all, cur_all, csr_all);

    // 7) layer-1 aggregation (fp8 gather, L3-resident)
    k_agg1<<<2 * (cD0 / 4), 256, 0, stream>>>(
        qu, off0, csr0, aggR, qm, off1, csr1, aggB);
    // 8) layer-1 dual GEMM: [h1m | h1u], BM=128, mtiles=313
    k_gemm2<128, cDIN, cDH, true, true><<<2 * 313 * (cDH / 128), 256, 0, stream>>>(
        xmb, aggR, wt + 0 * 131072, wt + 1 * 131072, b1r, h1m,
        xub, aggB, wt + 2 * 131072, wt + 3 * 131072, b1b, h1u, 313);

    // 9) layer-2 aggregation (bf16 gather)
    k_agg2<<<2 * (cD1 / 4), 256, 0, stream>>>(
        h1u, off2, csr2, agg2R, h1m, off3, csr3, agg2B);
    // 10) layer-2 dual GEMM: [m2 | u2], BM=64, mtiles=128
    k_gemm2<64, cDH, cDOUT, false, false><<<2 * 128 * (cDOUT / 128), 256, 0, stream>>>(
        h1m, agg2R, wt + 4 * 131072, wt + 5 * 131072, b2r, out_m2,
        h1u, agg2B, wt + 6 * 131072, wt + 7 * 131072, b2b, out_u2, 128);
}

// Round 12
// 457.479 us; speedup vs baseline: 1.0168x; 1.0168x over previous
//
#include <hip/hip_runtime.h>
#include <stdint.h>

#define DEV_INLINE __device__ __forceinline__

constexpr int cS0 = 200000, cD0 = 40000, cD1 = 8192;
constexpr int cE0 = 640000, cE1 = 131072;
constexpr int cDIN = 256, cDH = 512, cDOUT = 256;

// padded per-relation node-region sizes
constexpr int P0 = 40960, P1 = 9216;
constexpr int NTOT = 2 * P0 + 2 * P1;   // 100352
constexpr int NBLK = NTOT / 1024;       // 98
constexpr int ETOT = 2 * cE0 + 2 * cE1; // 1542144
constexpr int MPADI = 40064;            // cD0 padded for BM=128 tiles

// front kernel partition (cvt: one 16-float unit per thread -> 16B fp8 store)
constexpr long N16  = (long)cS0 * cDIN / 16;     // 16-float units per table (3.2M)
constexpr long NQB16 = (long)MPADI * cDIN / 16;  // units needing bf16 mini copy
constexpr int NCVT_BLK = (int)(2 * N16 / 256);   // 25000
constexpr int NWT_BLK  = 1024;                   // 32x32 transpose tiles
constexpr int NDEG_BLK = (ETOT + 255) / 256;     // 6024

typedef __attribute__((ext_vector_type(8))) short bf16x8_t;
typedef __attribute__((ext_vector_type(4))) float f32x4_t;
typedef __attribute__((ext_vector_type(2))) float fp32x2_t;

#if __has_builtin(__builtin_amdgcn_cvt_pk_f32_fp8) && __has_builtin(__builtin_amdgcn_cvt_pk_fp8_f32)
#define HWFP8 1
#else
#define HWFP8 0
#endif

DEV_INLINE float bf2f(unsigned short u) {
    union { unsigned int i; float f; } x; x.i = ((unsigned int)u) << 16; return x.f;
}
DEV_INLINE unsigned short f2bf(float f) {
    union { float f; unsigned int i; } x; x.f = f;
    unsigned int r = x.i + 0x7FFF + ((x.i >> 16) & 1);
    return (unsigned short)(r >> 16);
}

#if !HWFP8
DEV_INLINE unsigned char f2fp8s(float f) {
    union { float f; unsigned int u; } x; x.f = f;
    unsigned int s = (x.u >> 24) & 0x80;
    x.u &= 0x7FFFFFFF;
    if (x.f >= 448.f) return (unsigned char)(s | 0x7E);
    int e = (int)(x.u >> 23) - 127;
    if (e < -6) {
        int m = (int)(x.f * 512.0f + 0.5f);
        return (unsigned char)(m >= 8 ? (s | 0x08) : (s | m));
    }
    unsigned int r = x.u + 0x7FFFF + ((x.u >> 20) & 1);
    e = (int)(r >> 23) - 127;
    if (e > 8) return (unsigned char)(s | 0x7E);
    return (unsigned char)(s | ((unsigned)(e + 7) << 3) | ((r >> 20) & 7));
}
DEV_INLINE float fp82f(unsigned char b) {
    int e = (b >> 3) & 15, m = b & 7;
    float f;
    if (e == 0) f = (float)m * 0x1p-9f;
    else { union { unsigned int u; float f; } x; x.u = ((unsigned int)(e + 120) << 23) | ((unsigned int)m << 20); f = x.f; }
    return (b & 0x80) ? -f : f;
}
#endif

DEV_INLINE unsigned int pack4_fp8(f32x4_t u) {
#if HWFP8
    int w0 = __builtin_amdgcn_cvt_pk_fp8_f32(u.x, u.y, 0, false);
    w0 = __builtin_amdgcn_cvt_pk_fp8_f32(u.z, u.w, w0, true);
    return (unsigned)w0;
#else
    return (unsigned)f2fp8s(u.x) | ((unsigned)f2fp8s(u.y) << 8) |
           ((unsigned)f2fp8s(u.z) << 16) | ((unsigned)f2fp8s(u.w) << 24);
#endif
}

DEV_INLINE void gload_lds16(const void* g, void* l) {
    __builtin_amdgcn_global_load_lds(
        (__attribute__((address_space(1))) void*)(uintptr_t)g,
        (__attribute__((address_space(3))) void*)(uintptr_t)l,
        16, 0, 0);
}

struct WPtrs { const float* w[8]; };

// ---------------- fused front ----------------
// cvt: one-shot threads, 16 floats/thread (4 indep float4 loads), ONE uint4 fp8 store (16B);
//      mini bf16 rows get two uint4 stores (16B each). R4-measured-best store shape.
// wt:  LDS 32x33 tile transpose, coalesced both sides.
// deg: edge-dst histogram.

__global__ __launch_bounds__(256) void k_front(
    const float* __restrict__ xu, const float* __restrict__ xm,
    unsigned char* __restrict__ qu, unsigned char* __restrict__ qm,
    unsigned short* __restrict__ mu, unsigned short* __restrict__ mm,
    WPtrs W, unsigned short* __restrict__ wt,
    const int* __restrict__ d0, const int* __restrict__ d1,
    const int* __restrict__ d2, const int* __restrict__ d3,
    int* __restrict__ deg) {
    __shared__ float tile[32][33];
    int b = blockIdx.x;
    if (b < NCVT_BLK) {
        long i = (long)b * 256 + threadIdx.x;     // 16-float unit index
        const float* in; unsigned char* q8; unsigned short* mini;
        if (i >= N16) { in = xm; q8 = qm; mini = mm; i -= N16; }
        else          { in = xu; q8 = qu; mini = mu; }
        const f32x4_t* p = (const f32x4_t*)(in + i * 16);
        f32x4_t a = p[0], c = p[1], d = p[2], e = p[3];   // 4 independent loads
        uint4 q;
        q.x = pack4_fp8(a); q.y = pack4_fp8(c); q.z = pack4_fp8(d); q.w = pack4_fp8(e);
        *(uint4*)(q8 + i * 16) = q;                        // one 16B store
        if (i < NQB16) {
            union { unsigned short us[8]; uint4 v; } pk;
            pk.us[0] = f2bf(a.x); pk.us[1] = f2bf(a.y); pk.us[2] = f2bf(a.z); pk.us[3] = f2bf(a.w);
            pk.us[4] = f2bf(c.x); pk.us[5] = f2bf(c.y); pk.us[6] = f2bf(c.z); pk.us[7] = f2bf(c.w);
            *(uint4*)(mini + i * 16) = pk.v;
            pk.us[0] = f2bf(d.x); pk.us[1] = f2bf(d.y); pk.us[2] = f2bf(d.z); pk.us[3] = f2bf(d.w);
            pk.us[4] = f2bf(e.x); pk.us[5] = f2bf(e.y); pk.us[6] = f2bf(e.z); pk.us[7] = f2bf(e.w);
            *(uint4*)(mini + i * 16 + 8) = pk.v;
        }
        return;
    }
    b -= NCVT_BLK;
    if (b < NWT_BLK) {                            // W [K][N] fp32 -> Wt [N][K] bf16, LDS transpose
        int slot = b >> 7, t2 = b & 127;
        int K, N, k0, n0;
        if (slot < 4) { K = cDIN; N = cDH;  k0 = (t2 & 7) * 32;  n0 = (t2 >> 3) * 32; }
        else          { K = cDH;  N = cDOUT; k0 = (t2 & 15) * 32; n0 = (t2 >> 4) * 32; }
        const float* Wp = W.w[slot];
        int c = threadIdx.x & 31, ty = threadIdx.x >> 5;
#pragma unroll
        for (int it = 0; it < 4; ++it) {
            int r = it * 8 + ty;
            tile[r][c] = Wp[(size_t)(k0 + r) * N + n0 + c];
        }
        __syncthreads();
        unsigned short* wo = wt + (size_t)slot * 131072;
#pragma unroll
        for (int it = 0; it < 4; ++it) {
            int r = it * 8 + ty;
            wo[(size_t)(n0 + r) * K + k0 + c] = f2bf(tile[c][r]);
        }
        return;
    }
    b -= NWT_BLK;
    int i = b * 256 + threadIdx.x;
    if (i >= ETOT) return;
    const int* dp; int base, noff;
    if (i < cE0)                { dp = d0; base = 0;             noff = 0; }
    else if (i < 2 * cE0)       { dp = d1; base = cE0;           noff = P0; }
    else if (i < 2 * cE0 + cE1) { dp = d2; base = 2 * cE0;       noff = 2 * P0; }
    else                        { dp = d3; base = 2 * cE0 + cE1; noff = 2 * P0 + P1; }
    atomicAdd(&deg[noff + dp[i - base]], 1);
}

// ---------------- CSR scan + fill ----------------

__global__ __launch_bounds__(256) void k_scanA(const int* __restrict__ deg, int* __restrict__ off,
                                               int* __restrict__ btot) {
    __shared__ int buf[256];
    int t = threadIdx.x;
    long base = (long)blockIdx.x * 1024;
    int4 v = *(const int4*)(deg + base + t * 4);
    int s1 = v.x + v.y, s2 = s1 + v.z, ts = s2 + v.w;
    buf[t] = ts; __syncthreads();
    for (int o = 1; o < 256; o <<= 1) {
        int u = (t >= o) ? buf[t - o] : 0;
        __syncthreads(); buf[t] += u; __syncthreads();
    }
    int ex = buf[t] - ts;
    int4 w; w.x = ex; w.y = ex + v.x; w.z = ex + s1; w.w = ex + s2;
    *(int4*)(off + base + t * 4) = w;
    if (t == 255) btot[blockIdx.x] = buf[255];
}

__global__ void k_scanB(int* __restrict__ bt) {
    __shared__ int buf[128];
    __shared__ int seg[128];
    int t = threadIdx.x;
    int s = (t >= 89) ? 3 : (t >= 80) ? 2 : (t >= 40) ? 1 : 0;
    int v = (t < NBLK) ? bt[t] : 0;
    buf[t] = v; seg[t] = s; __syncthreads();
    for (int o = 1; o < 128; o <<= 1) {
        int u = 0;
        if (t >= o && seg[t - o] == s) u = buf[t - o];
        __syncthreads(); buf[t] += u; __syncthreads();
    }
    if (t < NBLK) bt[t] = buf[t] - v;   // exclusive within segment
}

__global__ __launch_bounds__(256) void k_scanC(int* __restrict__ off, const int* __restrict__ bt) {
    int t = threadIdx.x;
    long base = (long)blockIdx.x * 1024;
    int bo = bt[blockIdx.x];
    int4 v = *(int4*)(off + base + t * 4);
    v.x += bo; v.y += bo; v.z += bo; v.w += bo;
    *(int4*)(off + base + t * 4) = v;
}

__global__ __launch_bounds__(256) void k_fill_all(
    const int* __restrict__ s0, const int* __restrict__ d0, const int* __restrict__ s1, const int* __restrict__ d1,
    const int* __restrict__ s2, const int* __restrict__ d2, const int* __restrict__ s3, const int* __restrict__ d3,
    const int* __restrict__ off, int* __restrict__ cur, int* __restrict__ csr) {
    int i = blockIdx.x * 256 + threadIdx.x;
    if (i >= ETOT) return;
    const int* sp; const int* dp; int base, noff, cbase;
    if (i < cE0)                { sp = s0; dp = d0; base = 0;             noff = 0;           cbase = 0; }
    else if (i < 2 * cE0)       { sp = s1; dp = d1; base = cE0;           noff = P0;          cbase = cE0; }
    else if (i < 2 * cE0 + cE1) { sp = s2; dp = d2; base = 2 * cE0;       noff = 2 * P0;      cbase = 2 * cE0; }
    else                        { sp = s3; dp = d3; base = 2 * cE0 + cE1; noff = 2 * P0 + P1; cbase = 2 * cE0 + cE1; }
    int li = i - base;
    int d = dp[li];
    int p = atomicAdd(&cur[noff + d], 1);
    csr[cbase + off[noff + d] + p] = sp[li];
}

// ---------------- layer-1 mean aggregation: fp8 gather (L3-resident tables), bf16 out ----------------

__global__ __launch_bounds__(256) void k_agg1(
    const unsigned char* __restrict__ q0, const int* __restrict__ off0, const int* __restrict__ csr0,
    unsigned short* __restrict__ o0,
    const unsigned char* __restrict__ q1, const int* __restrict__ off1, const int* __restrict__ csr1,
    unsigned short* __restrict__ o1) {
    constexpr int U = 16;
    int nb = cD0 / 4;
    int b = blockIdx.x;
    const unsigned char* xq; const int* off; const int* csr; unsigned short* out;
    if (b >= nb) { xq = q1; off = off1; csr = csr1; out = o1; b -= nb; }
    else         { xq = q0; off = off0; csr = csr0; out = o0; }
    int lane = threadIdx.x & 63;
    int d = b * 4 + (threadIdx.x >> 6);

    float a0 = 0.f, a1 = 0.f, a2 = 0.f, a3 = 0.f;
    int p0 = off[d], p1 = off[d + 1];

    for (int p = p0; p < p1; p += U) {
        int idx[U];
#pragma unroll
        for (int u = 0; u < U; ++u) {
            int q = p + u;
            idx[u] = (q < p1) ? csr[q] : -1;
        }
#pragma unroll
        for (int u = 0; u < U; ++u) {
            if (idx[u] >= 0) {
                unsigned int w = *(const unsigned int*)(xq + (size_t)idx[u] * cDIN + lane * 4);
#if HWFP8
                fp32x2_t lo = __builtin_amdgcn_cvt_pk_f32_fp8((int)w, false);
                fp32x2_t hi = __builtin_amdgcn_cvt_pk_f32_fp8((int)w, true);
                a0 += lo[0]; a1 += lo[1]; a2 += hi[0]; a3 += hi[1];
#else
                a0 += fp82f(w & 0xFF); a1 += fp82f((w >> 8) & 0xFF);
                a2 += fp82f((w >> 16) & 0xFF); a3 += fp82f(w >> 24);
#endif
            }
        }
    }
    int dg = p1 - p0;
    float sc = 1.0f / (float)(dg > 1 ? dg : 1);
    union { unsigned short us[4]; uint2 v2; } pk;
    pk.us[0] = f2bf(a0 * sc); pk.us[1] = f2bf(a1 * sc);
    pk.us[2] = f2bf(a2 * sc); pk.us[3] = f2bf(a3 * sc);
    *(uint2*)(out + (size_t)d * cDIN + (size_t)lane * 4) = pk.v2;
}

// ---------------- layer-2 mean aggregation (bf16, K=512) ----------------

__global__ __launch_bounds__(256) void k_agg2(
    const unsigned short* __restrict__ x0, const int* __restrict__ off0, const int* __restrict__ csr0,
    unsigned short* __restrict__ o0,
    const unsigned short* __restrict__ x1, const int* __restrict__ off1, const int* __restrict__ csr1,
    unsigned short* __restrict__ o1) {
    constexpr int K = cDH, U = 8;
    int nb = cD1 / 4;
    int b = blockIdx.x;
    const unsigned short* xs; const int* off; const int* csr; unsigned short* out;
    if (b >= nb) { xs = x1; off = off1; csr = csr1; out = o1; b -= nb; }
    else         { xs = x0; off = off0; csr = csr0; out = o0; }
    int lane = threadIdx.x & 63;
    int d = b * 4 + (threadIdx.x >> 6);

    float acc[8];
#pragma unroll
    for (int i = 0; i < 8; i++) acc[i] = 0.f;
    int p0 = off[d], p1 = off[d + 1];

    for (int p = p0; p < p1; p += U) {
        int idx[U];
#pragma unroll
        for (int u = 0; u < U; ++u) {
            int q = p + u;
            idx[u] = (q < p1) ? csr[q] : -1;
        }
#pragma unroll
        for (int u = 0; u < U; ++u) {
            if (idx[u] >= 0) {
                uint4 v = *(const uint4*)(xs + (size_t)idx[u] * K + lane * 8);
                const unsigned short* us = (const unsigned short*)&v;
#pragma unroll
                for (int i = 0; i < 8; ++i) acc[i] += bf2f(us[i]);
            }
        }
    }
    int dg = p1 - p0;
    float sc = 1.0f / (float)(dg > 1 ? dg : 1);
    union { unsigned short us[8]; uint4 v4; } pk;
#pragma unroll
    for (int i = 0; i < 8; i++) pk.us[i] = f2bf(acc[i] * sc);
    *(uint4*)(out + (size_t)d * K + (size_t)lane * 8) = pk.v4;
}

// ---------------- fused SAGE GEMM (MFMA bf16), 2 relations per launch ----------------

template <int BM, int KSEG, int N, bool OUT_BF16, bool RELU>
__global__ __launch_bounds__(256) void k_gemm2(
    const unsigned short* __restrict__ aself0, const unsigned short* __restrict__ aagg0,
    const unsigned short* __restrict__ bts0, const unsigned short* __restrict__ btn0,
    const float* __restrict__ bias0, void* __restrict__ out0,
    const unsigned short* __restrict__ aself1, const unsigned short* __restrict__ aagg1,
    const unsigned short* __restrict__ bts1, const unsigned short* __restrict__ btn1,
    const float* __restrict__ bias1, void* __restrict__ out1,
    int mtiles) {
    constexpr int BN = 128, BK = 64;
    constexpr int H = KSEG / BK, NSTEP = 2 * H;
    constexpr int WROWS = BM / 2, FM = WROWS / 16;
    constexpr int AIT = BM / 32;
    __shared__ __align__(16) unsigned short As[2][BM * BK];
    __shared__ __align__(16) unsigned short Bs[2][BN * BK];

    const int tiles_n = N / BN;
    const int gpr = mtiles * tiles_n;
    int b = blockIdx.x;
    {
        int cpx = gridDim.x >> 3;
        b = (b & 7) * cpx + (b >> 3);
    }
    const unsigned short *aself, *aagg, *bts, *btn; const float* bias; void* out;
    if (b >= gpr) { b -= gpr; aself = aself1; aagg = aagg1; bts = bts1; btn = btn1; bias = bias1; out = out1; }
    else          {           aself = aself0; aagg = aagg0; bts = bts0; btn = btn0; bias = bias0; out = out0; }
    const int m0 = (b / tiles_n) * BM;
    const int n0 = (b % tiles_n) * BN;
    const int t = threadIdx.x, lane = t & 63, wave = t >> 6;
    const int wr = wave >> 1, wc = wave & 1;
    const int l15 = lane & 15, l4 = lane >> 4;

    f32x4_t acc[FM][4];
    const f32x4_t zero = {0.f, 0.f, 0.f, 0.f};
#pragma unroll
    for (int i = 0; i < FM; i++)
#pragma unroll
        for (int j = 0; j < 4; j++) acc[i][j] = zero;

    auto stage = [&](int buf, int s) {
        const int seg = (s >= H) ? 1 : 0;
        const int k0 = (s - seg * H) * BK;
        const unsigned short* A = seg ? aagg : aself;
        const unsigned short* B = seg ? btn : bts;
#pragma unroll
        for (int it = 0; it < AIT; ++it) {
            int c = it * 256 + t;
            int row = c >> 3;
            int lch = (c & 7) ^ (row & 7);
            gload_lds16(A + (size_t)(m0 + row) * KSEG + k0 + lch * 8,
                        (char*)&As[buf][0] + (it * 256 + wave * 64) * 16);
        }
#pragma unroll
        for (int it = 0; it < 4; ++it) {
            int c = it * 256 + t;
            int row = c >> 3;
            int lch = (c & 7) ^ (row & 7);
            gload_lds16(B + (size_t)(n0 + row) * KSEG + k0 + lch * 8,
                        (char*)&Bs[buf][0] + (it * 256 + wave * 64) * 16);
        }
    };

    int cur = 0;
    stage(0, 0);
    for (int s = 0; s < NSTEP; ++s) {
        __syncthreads();
        if (s + 1 < NSTEP) stage(cur ^ 1, s + 1);
        const char* Ab = (const char*)&As[cur][0];
        const char* Bb = (const char*)&Bs[cur][0];
        bf16x8_t a[FM][2], bb[4][2];
#pragma unroll
        for (int fm = 0; fm < FM; ++fm) {
            int row = wr * WROWS + fm * 16 + l15;
#pragma unroll
            for (int ks = 0; ks < 2; ++ks) {
                int pc = (ks * 4 + l4) ^ (row & 7);
                a[fm][ks] = *(const bf16x8_t*)(Ab + row * 128 + pc * 16);
            }
        }
#pragma unroll
        for (int fn = 0; fn < 4; ++fn) {
            int row = wc * 64 + fn * 16 + l15;
#pragma unroll
            for (int ks = 0; ks < 2; ++ks) {
                int pc = (ks * 4 + l4) ^ (row & 7);
                bb[fn][ks] = *(const bf16x8_t*)(Bb + row * 128 + pc * 16);
            }
        }
#pragma unroll
        for (int ks = 0; ks < 2; ++ks)
#pragma unroll
            for (int fm = 0; fm < FM; ++fm)
#pragma unroll
                for (int fn = 0; fn < 4; ++fn)
                    acc[fm][fn] = __builtin_amdgcn_mfma_f32_16x16x32_bf16(
                        a[fm][ks], bb[fn][ks], acc[fm][fn], 0, 0, 0);
        cur ^= 1;
    }

#pragma unroll
    for (int fm = 0; fm < FM; ++fm) {
#pragma unroll
        for (int fn = 0; fn < 4; ++fn) {
            int col = n0 + wc * 64 + fn * 16 + l15;
            float bv = bias[col];
            f32x4_t v = acc[fm][fn];
#pragma unroll
            for (int r = 0; r < 4; ++r) {
                int rowg = m0 + wr * WROWS + fm * 16 + l4 * 4 + r;
                float o = v[r] + bv;
                if (RELU) o = fmaxf(o, 0.f);
                if constexpr (OUT_BF16)
                    ((unsigned short*)out)[(size_t)rowg * N + col] = f2bf(o);
                else
                    ((float*)out)[(size_t)rowg * N + col] = o;
            }
        }
    }
}

// ---------------- launch ----------------

extern "C" void kernel_launch(void* const* d_in, const int* in_sizes, int n_in,
                              void* d_out, int out_size, void* d_ws, size_t ws_size,
                              hipStream_t stream) {
    const float* x_user  = (const float*)d_in[0];
    const float* x_movie = (const float*)d_in[1];
    const float* W1r_n = (const float*)d_in[2];
    const float* W1r_s = (const float*)d_in[3];
    const float* b1r   = (const float*)d_in[4];
    const float* W1b_n = (const float*)d_in[5];
    const float* W1b_s = (const float*)d_in[6];
    const float* b1b   = (const float*)d_in[7];
    const float* W2r_n = (const float*)d_in[8];
    const float* W2r_s = (const float*)d_in[9];
    const float* b2r   = (const float*)d_in[10];
    const float* W2b_n = (const float*)d_in[11];
    const float* W2b_s = (const float*)d_in[12];
    const float* b2b   = (const float*)d_in[13];
    const int* e0r_src = (const int*)d_in[14];
    const int* e0r_dst = (const int*)d_in[15];
    const int* e0b_src = (const int*)d_in[16];
    const int* e0b_dst = (const int*)d_in[17];
    const int* e1r_src = (const int*)d_in[18];
    const int* e1r_dst = (const int*)d_in[19];
    const int* e1b_src = (const int*)d_in[20];
    const int* e1b_dst = (const int*)d_in[21];

    // ---- workspace layout ----
    constexpr size_t MPAD = MPADI;
    char* w = (char*)d_ws;
    size_t o = 0;
    auto take = [&](size_t bytes) -> void* {
        void* p = w + o; o += (bytes + 255) & ~(size_t)255; return p;
    };
    unsigned short* h1m   = (unsigned short*)take(MPAD * cDH * 2);
    unsigned short* h1u   = (unsigned short*)take(MPAD * cDH * 2);
    unsigned short* aggR  = (unsigned short*)take(MPAD * cDIN * 2);
    unsigned short* aggB  = (unsigned short*)take(MPAD * cDIN * 2);
    unsigned short* agg2R = (unsigned short*)take((size_t)cD1 * cDH * 2);
    unsigned short* agg2B = (unsigned short*)take((size_t)cD1 * cDH * 2);
    unsigned short* wt    = (unsigned short*)take((size_t)8 * 131072 * 2);
    unsigned char*  qu    = (unsigned char*)take((size_t)cS0 * cDIN);      // fp8 tables
    unsigned char*  qm    = (unsigned char*)take((size_t)cS0 * cDIN);
    unsigned short* xub   = (unsigned short*)take(MPAD * cDIN * 2);        // bf16 minis
    unsigned short* xmb   = (unsigned short*)take(MPAD * cDIN * 2);
    int* deg_all = (int*)take((size_t)2 * NTOT * 4);   // deg + cur contiguous
    int* cur_all = deg_all + NTOT;
    int* off_all = (int*)take((size_t)NTOT * 4);
    int* btot    = (int*)take(512);
    int* csr_all = (int*)take((size_t)ETOT * 4);
    if (ws_size < o) return;  // insufficient workspace: fail visibly

    const int* off0 = off_all;
    const int* off1 = off_all + P0;
    const int* off2 = off_all + 2 * P0;
    const int* off3 = off_all + 2 * P0 + P1;
    const int* csr0 = csr_all;
    const int* csr1 = csr_all + cE0;
    const int* csr2 = csr_all + 2 * cE0;
    const int* csr3 = csr_all + 2 * cE0 + cE1;

    float* out_u2 = (float*)d_out;
    float* out_m2 = (float*)d_out + (size_t)cD1 * cDOUT;

    // 1) zero deg+cur
    hipMemsetAsync(deg_all, 0, (size_t)2 * NTOT * 4, stream);
    // 2) fused front: fp8+mini cvt (16B stores) | wt LDS transpose | degree count
    WPtrs WP;
    WP.w[0] = W1r_s; WP.w[1] = W1r_n; WP.w[2] = W1b_s; WP.w[3] = W1b_n;
    WP.w[4] = W2r_s; WP.w[5] = W2r_n; WP.w[6] = W2b_s; WP.w[7] = W2b_n;
    k_front<<<NCVT_BLK + NWT_BLK + NDEG_BLK, 256, 0, stream>>>(
        x_user, x_movie, qu, qm, xub, xmb, WP, wt,
        e0r_dst, e0b_dst, e1r_dst, e1b_dst, deg_all);
    // 3-5) scans
    k_scanA<<<NBLK, 256, 0, stream>>>(deg_all, off_all, btot);
    k_scanB<<<1, 128, 0, stream>>>(btot);
    k_scanC<<<NBLK, 256, 0, stream>>>(off_all, btot);
    // 6) CSR fill
    k_fill_all<<<(ETOT + 255) / 256, 256, 0, stream>>>(
        e0r_src, e0r_dst, e0b_src, e0b_dst, e1r_src, e1r_dst, e1b_src, e1b_dst,
        off_all, cur_all, csr_all);

    // 7) layer-1 aggregation (fp8 gather, L3-resident)
    k_agg1<<<2 * (cD0 / 4), 256, 0, stream>>>(
        qu, off0, csr0, aggR, qm, off1, csr1, aggB);
    // 8) layer-1 dual GEMM: [h1m | h1u], BM=128, mtiles=313
    k_gemm2<128, cDIN, cDH, true, true><<<2 * 313 * (cDH / 128), 256, 0, stream>>>(
        xmb, aggR, wt + 0 * 131072, wt + 1 * 131072, b1r, h1m,
        xub, aggB, wt + 2 * 131072, wt + 3 * 131072, b1b, h1u, 313);

    // 9) layer-2 aggregation (bf16 gather)
    k_agg2<<<2 * (cD1 / 4), 256, 0, stream>>>(
        h1u, off2, csr2, agg2R, h1m, off3, csr3, agg2B);
    // 10) layer-2 dual GEMM: [m2 | u2], BM=64, mtiles=128
    k_gemm2<64, cDH, cDOUT, false, false><<<2 * 128 * (cDOUT / 128), 256, 0, stream>>>(
        h1m, agg2R, wt + 4 * 131072, wt + 5 * 131072, b2r, out_m2,
        h1u, agg2B, wt + 6 * 131072, wt + 7 * 131072, b2b, out_u2, 128);
}

// Round 13
// 455.092 us; speedup vs baseline: 1.0221x; 1.0052x over previous
//
#include <hip/hip_runtime.h>
#include <stdint.h>

#define DEV_INLINE __device__ __forceinline__

constexpr int cS0 = 200000, cD0 = 40000, cD1 = 8192;
constexpr int cE0 = 640000, cE1 = 131072;
constexpr int cDIN = 256, cDH = 512, cDOUT = 256;

// padded per-relation node-region sizes
constexpr int P0 = 40960, P1 = 9216;
constexpr int NTOT = 2 * P0 + 2 * P1;   // 100352
constexpr int NBLK = NTOT / 1024;       // 98
constexpr int ETOT = 2 * cE0 + 2 * cE1; // 1542144
constexpr int MPADI = 40064;            // cD0 padded for BM=128 tiles

// front kernel partition (cvt: R4-measured-best shape, 8 floats/thread -> one uint4 store)
constexpr long N8 = (long)cS0 * cDIN / 8;        // 8-float units per table (6.4M)
constexpr int NCVT_BLK = (int)(2 * N8 / 256);    // 50000
constexpr int NWT_BLK  = 1024;                   // 32x32 transpose tiles
constexpr int NDEG_BLK = (ETOT + 255) / 256;     // 6024

typedef __attribute__((ext_vector_type(8))) short bf16x8_t;
typedef __attribute__((ext_vector_type(4))) float f32x4_t;

DEV_INLINE float bf2f(unsigned short u) {
    union { unsigned int i; float f; } x; x.i = ((unsigned int)u) << 16; return x.f;
}
DEV_INLINE unsigned short f2bf(float f) {
    union { float f; unsigned int i; } x; x.f = f;
    unsigned int r = x.i + 0x7FFF + ((x.i >> 16) & 1);
    return (unsigned short)(r >> 16);
}

DEV_INLINE void gload_lds16(const void* g, void* l) {
    __builtin_amdgcn_global_load_lds(
        (__attribute__((address_space(1))) void*)(uintptr_t)g,
        (__attribute__((address_space(3))) void*)(uintptr_t)l,
        16, 0, 0);
}

struct WPtrs { const float* w[8]; };

// ---------------- fused front: full-table bf16 cvt | wt LDS transpose | degree ----------------

__global__ __launch_bounds__(256) void k_front(
    const float* __restrict__ xu, const float* __restrict__ xm,
    unsigned short* __restrict__ ou, unsigned short* __restrict__ om,
    WPtrs W, unsigned short* __restrict__ wt,
    const int* __restrict__ d0, const int* __restrict__ d1,
    const int* __restrict__ d2, const int* __restrict__ d3,
    int* __restrict__ deg) {
    __shared__ float tile[32][33];
    int b = blockIdx.x;
    if (b < NCVT_BLK) {
        // R4-measured-best: 8 floats/thread, 2 float4 loads, ONE uint4 store
        long i = (long)b * 256 + threadIdx.x;
        const float* in; unsigned short* out;
        if (i >= N8) { in = xm; out = om; i -= N8; } else { in = xu; out = ou; }
        const float4* p = (const float4*)(in + i * 8);
        float4 u = p[0], v = p[1];
        union { unsigned short us[8]; uint4 q; } pk;
        pk.us[0] = f2bf(u.x); pk.us[1] = f2bf(u.y); pk.us[2] = f2bf(u.z); pk.us[3] = f2bf(u.w);
        pk.us[4] = f2bf(v.x); pk.us[5] = f2bf(v.y); pk.us[6] = f2bf(v.z); pk.us[7] = f2bf(v.w);
        *(uint4*)(out + i * 8) = pk.q;
        return;
    }
    b -= NCVT_BLK;
    if (b < NWT_BLK) {                            // W [K][N] fp32 -> Wt [N][K] bf16, LDS transpose
        int slot = b >> 7, t2 = b & 127;
        int K, N, k0, n0;
        if (slot < 4) { K = cDIN; N = cDH;  k0 = (t2 & 7) * 32;  n0 = (t2 >> 3) * 32; }
        else          { K = cDH;  N = cDOUT; k0 = (t2 & 15) * 32; n0 = (t2 >> 4) * 32; }
        const float* Wp = W.w[slot];
        int c = threadIdx.x & 31, ty = threadIdx.x >> 5;
#pragma unroll
        for (int it = 0; it < 4; ++it) {
            int r = it * 8 + ty;
            tile[r][c] = Wp[(size_t)(k0 + r) * N + n0 + c];   // coalesced in c
        }
        __syncthreads();
        unsigned short* wo = wt + (size_t)slot * 131072;
#pragma unroll
        for (int it = 0; it < 4; ++it) {
            int r = it * 8 + ty;
            wo[(size_t)(n0 + r) * K + k0 + c] = f2bf(tile[c][r]);  // coalesced in c
        }
        return;
    }
    b -= NWT_BLK;
    int i = b * 256 + threadIdx.x;
    if (i >= ETOT) return;
    const int* dp; int base, noff;
    if (i < cE0)                { dp = d0; base = 0;             noff = 0; }
    else if (i < 2 * cE0)       { dp = d1; base = cE0;           noff = P0; }
    else if (i < 2 * cE0 + cE1) { dp = d2; base = 2 * cE0;       noff = 2 * P0; }
    else                        { dp = d3; base = 2 * cE0 + cE1; noff = 2 * P0 + P1; }
    atomicAdd(&deg[noff + dp[i - base]], 1);
}

// ---------------- CSR scan + fill ----------------

__global__ __launch_bounds__(256) void k_scanA(const int* __restrict__ deg, int* __restrict__ off,
                                               int* __restrict__ btot) {
    __shared__ int buf[256];
    int t = threadIdx.x;
    long base = (long)blockIdx.x * 1024;
    int4 v = *(const int4*)(deg + base + t * 4);
    int s1 = v.x + v.y, s2 = s1 + v.z, ts = s2 + v.w;
    buf[t] = ts; __syncthreads();
    for (int o = 1; o < 256; o <<= 1) {
        int u = (t >= o) ? buf[t - o] : 0;
        __syncthreads(); buf[t] += u; __syncthreads();
    }
    int ex = buf[t] - ts;
    int4 w; w.x = ex; w.y = ex + v.x; w.z = ex + s1; w.w = ex + s2;
    *(int4*)(off + base + t * 4) = w;
    if (t == 255) btot[blockIdx.x] = buf[255];
}

__global__ void k_scanB(int* __restrict__ bt) {
    __shared__ int buf[128];
    __shared__ int seg[128];
    int t = threadIdx.x;
    int s = (t >= 89) ? 3 : (t >= 80) ? 2 : (t >= 40) ? 1 : 0;
    int v = (t < NBLK) ? bt[t] : 0;
    buf[t] = v; seg[t] = s; __syncthreads();
    for (int o = 1; o < 128; o <<= 1) {
        int u = 0;
        if (t >= o && seg[t - o] == s) u = buf[t - o];
        __syncthreads(); buf[t] += u; __syncthreads();
    }
    if (t < NBLK) bt[t] = buf[t] - v;   // exclusive within segment
}

__global__ __launch_bounds__(256) void k_scanC(int* __restrict__ off, const int* __restrict__ bt) {
    int t = threadIdx.x;
    long base = (long)blockIdx.x * 1024;
    int bo = bt[blockIdx.x];
    int4 v = *(int4*)(off + base + t * 4);
    v.x += bo; v.y += bo; v.z += bo; v.w += bo;
    *(int4*)(off + base + t * 4) = v;
}

__global__ __launch_bounds__(256) void k_fill_all(
    const int* __restrict__ s0, const int* __restrict__ d0, const int* __restrict__ s1, const int* __restrict__ d1,
    const int* __restrict__ s2, const int* __restrict__ d2, const int* __restrict__ s3, const int* __restrict__ d3,
    const int* __restrict__ off, int* __restrict__ cur, int* __restrict__ csr) {
    int i = blockIdx.x * 256 + threadIdx.x;
    if (i >= ETOT) return;
    const int* sp; const int* dp; int base, noff, cbase;
    if (i < cE0)                { sp = s0; dp = d0; base = 0;             noff = 0;           cbase = 0; }
    else if (i < 2 * cE0)       { sp = s1; dp = d1; base = cE0;           noff = P0;          cbase = cE0; }
    else if (i < 2 * cE0 + cE1) { sp = s2; dp = d2; base = 2 * cE0;       noff = 2 * P0;      cbase = 2 * cE0; }
    else                        { sp = s3; dp = d3; base = 2 * cE0 + cE1; noff = 2 * P0 + P1; cbase = 2 * cE0 + cE1; }
    int li = i - base;
    int d = dp[li];
    int p = atomicAdd(&cur[noff + d], 1);
    csr[cbase + off[noff + d] + p] = sp[li];
}

// ---------------- merged mean aggregation (2 relations per launch), bf16 in/out ----------------
// K=256: half-wave (32 lanes) per edge slot, 2 edge slots/wave, x8 unroll -> 16 loads in flight.
// K=512: full wave per edge, x8 unroll -> 8 loads in flight.

template <int K>
__global__ __launch_bounds__(256) void k_agg2(
    const unsigned short* __restrict__ x0, const int* __restrict__ off0, const int* __restrict__ csr0,
    unsigned short* __restrict__ o0,
    const unsigned short* __restrict__ x1, const int* __restrict__ off1, const int* __restrict__ csr1,
    unsigned short* __restrict__ o1, int ndst) {
    constexpr bool HALF = (K == 256);
    constexpr int ESTEP = HALF ? 2 : 1;     // edges per unroll slot
    constexpr int U = 8;
    int nb = ndst / 4;
    int b = blockIdx.x;
    const unsigned short* xs; const int* off; const int* csr; unsigned short* out;
    if (b >= nb) { xs = x1; off = off1; csr = csr1; out = o1; b -= nb; }
    else         { xs = x0; off = off0; csr = csr0; out = o0; }
    int lane = threadIdx.x & 63;
    int d = b * 4 + (threadIdx.x >> 6);
    int elane = HALF ? (lane & 31) : lane;  // 16B-granule index within row
    int eslot = HALF ? (lane >> 5) : 0;

    float acc[8];
#pragma unroll
    for (int i = 0; i < 8; i++) acc[i] = 0.f;
    int p0 = off[d], p1 = off[d + 1];

    for (int p = p0; p < p1; p += U * ESTEP) {
        int idx[U];
#pragma unroll
        for (int u = 0; u < U; ++u) {
            int q = p + u * ESTEP + eslot;
            idx[u] = (q < p1) ? csr[q] : -1;
        }
#pragma unroll
        for (int u = 0; u < U; ++u) {
            if (idx[u] >= 0) {
                uint4 v = *(const uint4*)(xs + (size_t)idx[u] * K + elane * 8);
                const unsigned short* us = (const unsigned short*)&v;
#pragma unroll
                for (int i = 0; i < 8; ++i) acc[i] += bf2f(us[i]);
            }
        }
    }
    if constexpr (HALF) {
#pragma unroll
        for (int i = 0; i < 8; ++i) acc[i] += __shfl_xor(acc[i], 32);
    }
    int dg = p1 - p0;
    float sc = 1.0f / (float)(dg > 1 ? dg : 1);
    union { unsigned short us[8]; uint4 v4; } pk;
#pragma unroll
    for (int i = 0; i < 8; i++) pk.us[i] = f2bf(acc[i] * sc);
    if (!HALF || lane < 32)
        *(uint4*)(out + (size_t)d * K + (size_t)elane * 8) = pk.v4;
}

// ---------------- fused SAGE GEMM (MFMA bf16), 2 relations per launch ----------------
// out = act( Aself@Wself + Aagg@Wneigh + bias ); K concat as 2 segments of KSEG.
// BMxBN tile (BN=128), BK=64; 4 waves 2x2; XOR chunk-swizzle on global src; XCD swizzle.

template <int BM, int KSEG, int N, bool OUT_BF16, bool RELU>
__global__ __launch_bounds__(256) void k_gemm2(
    const unsigned short* __restrict__ aself0, const unsigned short* __restrict__ aagg0,
    const unsigned short* __restrict__ bts0, const unsigned short* __restrict__ btn0,
    const float* __restrict__ bias0, void* __restrict__ out0,
    const unsigned short* __restrict__ aself1, const unsigned short* __restrict__ aagg1,
    const unsigned short* __restrict__ bts1, const unsigned short* __restrict__ btn1,
    const float* __restrict__ bias1, void* __restrict__ out1,
    int mtiles) {
    constexpr int BN = 128, BK = 64;
    constexpr int H = KSEG / BK, NSTEP = 2 * H;
    constexpr int WROWS = BM / 2, FM = WROWS / 16;
    constexpr int AIT = BM / 32;
    __shared__ __align__(16) unsigned short As[2][BM * BK];
    __shared__ __align__(16) unsigned short Bs[2][BN * BK];

    const int tiles_n = N / BN;
    const int gpr = mtiles * tiles_n;
    int b = blockIdx.x;
    {
        int cpx = gridDim.x >> 3;
        b = (b & 7) * cpx + (b >> 3);
    }
    const unsigned short *aself, *aagg, *bts, *btn; const float* bias; void* out;
    if (b >= gpr) { b -= gpr; aself = aself1; aagg = aagg1; bts = bts1; btn = btn1; bias = bias1; out = out1; }
    else          {           aself = aself0; aagg = aagg0; bts = bts0; btn = btn0; bias = bias0; out = out0; }
    const int m0 = (b / tiles_n) * BM;
    const int n0 = (b % tiles_n) * BN;
    const int t = threadIdx.x, lane = t & 63, wave = t >> 6;
    const int wr = wave >> 1, wc = wave & 1;
    const int l15 = lane & 15, l4 = lane >> 4;

    f32x4_t acc[FM][4];
    const f32x4_t zero = {0.f, 0.f, 0.f, 0.f};
#pragma unroll
    for (int i = 0; i < FM; i++)
#pragma unroll
        for (int j = 0; j < 4; j++) acc[i][j] = zero;

    auto stage = [&](int buf, int s) {
        const int seg = (s >= H) ? 1 : 0;
        const int k0 = (s - seg * H) * BK;
        const unsigned short* A = seg ? aagg : aself;
        const unsigned short* B = seg ? btn : bts;
#pragma unroll
        for (int it = 0; it < AIT; ++it) {
            int c = it * 256 + t;
            int row = c >> 3;
            int lch = (c & 7) ^ (row & 7);
            gload_lds16(A + (size_t)(m0 + row) * KSEG + k0 + lch * 8,
                        (char*)&As[buf][0] + (it * 256 + wave * 64) * 16);
        }
#pragma unroll
        for (int it = 0; it < 4; ++it) {
            int c = it * 256 + t;
            int row = c >> 3;
            int lch = (c & 7) ^ (row & 7);
            gload_lds16(B + (size_t)(n0 + row) * KSEG + k0 + lch * 8,
                        (char*)&Bs[buf][0] + (it * 256 + wave * 64) * 16);
        }
    };

    int cur = 0;
    stage(0, 0);
    for (int s = 0; s < NSTEP; ++s) {
        __syncthreads();
        if (s + 1 < NSTEP) stage(cur ^ 1, s + 1);
        const char* Ab = (const char*)&As[cur][0];
        const char* Bb = (const char*)&Bs[cur][0];
        bf16x8_t a[FM][2], bb[4][2];
#pragma unroll
        for (int fm = 0; fm < FM; ++fm) {
            int row = wr * WROWS + fm * 16 + l15;
#pragma unroll
            for (int ks = 0; ks < 2; ++ks) {
                int pc = (ks * 4 + l4) ^ (row & 7);
                a[fm][ks] = *(const bf16x8_t*)(Ab + row * 128 + pc * 16);
            }
        }
#pragma unroll
        for (int fn = 0; fn < 4; ++fn) {
            int row = wc * 64 + fn * 16 + l15;
#pragma unroll
            for (int ks = 0; ks < 2; ++ks) {
                int pc = (ks * 4 + l4) ^ (row & 7);
                bb[fn][ks] = *(const bf16x8_t*)(Bb + row * 128 + pc * 16);
            }
        }
#pragma unroll
        for (int ks = 0; ks < 2; ++ks)
#pragma unroll
            for (int fm = 0; fm < FM; ++fm)
#pragma unroll
                for (int fn = 0; fn < 4; ++fn)
                    acc[fm][fn] = __builtin_amdgcn_mfma_f32_16x16x32_bf16(
                        a[fm][ks], bb[fn][ks], acc[fm][fn], 0, 0, 0);
        cur ^= 1;
    }

#pragma unroll
    for (int fm = 0; fm < FM; ++fm) {
#pragma unroll
        for (int fn = 0; fn < 4; ++fn) {
            int col = n0 + wc * 64 + fn * 16 + l15;
            float bv = bias[col];
            f32x4_t v = acc[fm][fn];
#pragma unroll
            for (int r = 0; r < 4; ++r) {
                int rowg = m0 + wr * WROWS + fm * 16 + l4 * 4 + r;
                float o = v[r] + bv;
                if (RELU) o = fmaxf(o, 0.f);
                if constexpr (OUT_BF16)
                    ((unsigned short*)out)[(size_t)rowg * N + col] = f2bf(o);
                else
                    ((float*)out)[(size_t)rowg * N + col] = o;
            }
        }
    }
}

// ---------------- launch ----------------

extern "C" void kernel_launch(void* const* d_in, const int* in_sizes, int n_in,
                              void* d_out, int out_size, void* d_ws, size_t ws_size,
                              hipStream_t stream) {
    const float* x_user  = (const float*)d_in[0];
    const float* x_movie = (const float*)d_in[1];
    const float* W1r_n = (const float*)d_in[2];
    const float* W1r_s = (const float*)d_in[3];
    const float* b1r   = (const float*)d_in[4];
    const float* W1b_n = (const float*)d_in[5];
    const float* W1b_s = (const float*)d_in[6];
    const float* b1b   = (const float*)d_in[7];
    const float* W2r_n = (const float*)d_in[8];
    const float* W2r_s = (const float*)d_in[9];
    const float* b2r   = (const float*)d_in[10];
    const float* W2b_n = (const float*)d_in[11];
    const float* W2b_s = (const float*)d_in[12];
    const float* b2b   = (const float*)d_in[13];
    const int* e0r_src = (const int*)d_in[14];
    const int* e0r_dst = (const int*)d_in[15];
    const int* e0b_src = (const int*)d_in[16];
    const int* e0b_dst = (const int*)d_in[17];
    const int* e1r_src = (const int*)d_in[18];
    const int* e1r_dst = (const int*)d_in[19];
    const int* e1b_src = (const int*)d_in[20];
    const int* e1b_dst = (const int*)d_in[21];

    // ---- workspace layout ----
    constexpr size_t MPAD = MPADI;
    char* w = (char*)d_ws;
    size_t o = 0;
    auto take = [&](size_t bytes) -> void* {
        void* p = w + o; o += (bytes + 255) & ~(size_t)255; return p;
    };
    unsigned short* h1m   = (unsigned short*)take(MPAD * cDH * 2);
    unsigned short* h1u   = (unsigned short*)take(MPAD * cDH * 2);
    unsigned short* aggR  = (unsigned short*)take(MPAD * cDIN * 2);
    unsigned short* aggB  = (unsigned short*)take(MPAD * cDIN * 2);
    unsigned short* agg2R = (unsigned short*)take((size_t)cD1 * cDH * 2);
    unsigned short* agg2B = (unsigned short*)take((size_t)cD1 * cDH * 2);
    unsigned short* wt    = (unsigned short*)take((size_t)8 * 131072 * 2);
    unsigned short* xub   = (unsigned short*)take((size_t)cS0 * cDIN * 2);  // full bf16 tables
    unsigned short* xmb   = (unsigned short*)take((size_t)cS0 * cDIN * 2);
    int* deg_all = (int*)take((size_t)2 * NTOT * 4);   // deg + cur contiguous
    int* cur_all = deg_all + NTOT;
    int* off_all = (int*)take((size_t)NTOT * 4);
    int* btot    = (int*)take(512);
    int* csr_all = (int*)take((size_t)ETOT * 4);
    if (ws_size < o) return;  // insufficient workspace: fail visibly

    const int* off0 = off_all;
    const int* off1 = off_all + P0;
    const int* off2 = off_all + 2 * P0;
    const int* off3 = off_all + 2 * P0 + P1;
    const int* csr0 = csr_all;
    const int* csr1 = csr_all + cE0;
    const int* csr2 = csr_all + 2 * cE0;
    const int* csr3 = csr_all + 2 * cE0 + cE1;

    float* out_u2 = (float*)d_out;
    float* out_m2 = (float*)d_out + (size_t)cD1 * cDOUT;

    // 1) zero deg+cur
    hipMemsetAsync(deg_all, 0, (size_t)2 * NTOT * 4, stream);
    // 2) fused front: full-table bf16 cvt (R4 pattern) | wt LDS transpose | degree count
    WPtrs WP;
    WP.w[0] = W1r_s; WP.w[1] = W1r_n; WP.w[2] = W1b_s; WP.w[3] = W1b_n;
    WP.w[4] = W2r_s; WP.w[5] = W2r_n; WP.w[6] = W2b_s; WP.w[7] = W2b_n;
    k_front<<<NCVT_BLK + NWT_BLK + NDEG_BLK, 256, 0, stream>>>(
        x_user, x_movie, xub, xmb, WP, wt,
        e0r_dst, e0b_dst, e1r_dst, e1b_dst, deg_all);
    // 3-5) scans
    k_scanA<<<NBLK, 256, 0, stream>>>(deg_all, off_all, btot);
    k_scanB<<<1, 128, 0, stream>>>(btot);
    k_scanC<<<NBLK, 256, 0, stream>>>(off_all, btot);
    // 6) CSR fill
    k_fill_all<<<(ETOT + 255) / 256, 256, 0, stream>>>(
        e0r_src, e0r_dst, e0b_src, e0b_dst, e1r_src, e1r_dst, e1b_src, e1b_dst,
        off_all, cur_all, csr_all);

    // 7) layer-1 aggregation (bf16 gather, tables L3-fresh)
    k_agg2<cDIN><<<2 * (cD0 / 4), 256, 0, stream>>>(
        xub, off0, csr0, aggR, xmb, off1, csr1, aggB, cD0);
    // 8) layer-1 dual GEMM: [h1m | h1u], BM=128, mtiles=313
    k_gemm2<128, cDIN, cDH, true, true><<<2 * 313 * (cDH / 128), 256, 0, stream>>>(
        xmb, aggR, wt + 0 * 131072, wt + 1 * 131072, b1r, h1m,
        xub, aggB, wt + 2 * 131072, wt + 3 * 131072, b1b, h1u, 313);

    // 9) layer-2 aggregation (bf16 gather)
    k_agg2<cDH><<<2 * (cD1 / 4), 256, 0, stream>>>(
        h1u, off2, csr2, agg2R, h1m, off3, csr3, agg2B, cD1);
    // 10) layer-2 dual GEMM: [m2 | u2], BM=64, mtiles=128
    k_gemm2<64, cDH, cDOUT, false, false><<<2 * 128 * (cDOUT / 128), 256, 0, stream>>>(
        h1m, agg2R, wt + 4 * 131072, wt + 5 * 131072, b2r, out_m2,
        h1u, agg2B, wt + 6 * 131072, wt + 7 * 131072, b2b, out_u2, 128);
}